// Round 1
// baseline (2221.145 us; speedup 1.0000x reference)
//
#include <hip/hip_runtime.h>
#include <stdint.h>

typedef unsigned short u16;
typedef short short8 __attribute__((ext_vector_type(8)));
typedef float f32x4 __attribute__((ext_vector_type(4)));

#define NB 4
#define NS 2048
#define ND 1024
#define NH 16
#define NDK 64

__device__ __forceinline__ u16 f2bf(float f) {
    union { float f; uint32_t i; } x; x.f = f;
    uint32_t r = x.i + 0x7FFFu + ((x.i >> 16) & 1u);
    return (u16)(r >> 16);
}
__device__ __forceinline__ float bf2f(u16 u) {
    union { uint32_t i; float f; } x; x.i = ((uint32_t)u) << 16; return x.f;
}
__device__ __forceinline__ short8 cvt8(const float* __restrict__ p) {
    float4 a = *(const float4*)p;
    float4 b = *(const float4*)(p + 4);
    short8 r;
    r[0] = (short)f2bf(a.x); r[1] = (short)f2bf(a.y);
    r[2] = (short)f2bf(a.z); r[3] = (short)f2bf(a.w);
    r[4] = (short)f2bf(b.x); r[5] = (short)f2bf(b.y);
    r[6] = (short)f2bf(b.z); r[7] = (short)f2bf(b.w);
    return r;
}

// ---------------------------------------------------------------------------
// 128x128x32 MFMA GEMM: C = A[M,K] * Bt[N,K]^T + bias   (UNCHANGED this round)
// MODE 0: A=q/k fp32 [8192,1024], C -> Qh/Kh bf16 [B,H,S,DK], bias by n
// MODE 2: A=wv fp32 [1024,1024], Bt=v fp32 [8192,1024], C -> Vt bf16
//         [B,H,DK,S], bias by m
// MODE 3: A=X bf16 [8192,1024], Bt=wo fp32, C -> out fp32 [8192,1024], bias n
// ---------------------------------------------------------------------------
template<int MODE>
__global__ __launch_bounds__(256) void gemm128(
    const void* __restrict__ Av, const float* __restrict__ Bt,
    const float* __restrict__ bias, void* __restrict__ Cv)
{
    __shared__ __align__(16) u16 As[128 * 40];
    __shared__ __align__(16) u16 Bs[128 * 40];
    const int tid  = threadIdx.x;
    const int lane = tid & 63;
    const int w    = tid >> 6;
    const int wm   = (w >> 1) * 64;
    const int wn   = (w & 1) * 64;
    const int l15  = lane & 15;
    const int quad = lane >> 4;
    const int K    = 1024;
    int mt, nt;
    if (MODE == 2) { mt = blockIdx.x & 7; nt = blockIdx.x >> 3; }
    else           { mt = blockIdx.x >> 3; nt = blockIdx.x & 7; }
    const int m0 = mt * 128, n0 = nt * 128;

    f32x4 acc[4][4];
    const f32x4 zf = {0.f, 0.f, 0.f, 0.f};
#pragma unroll
    for (int i = 0; i < 4; ++i)
#pragma unroll
        for (int j = 0; j < 4; ++j) acc[i][j] = zf;

    const int r0 = tid >> 2;         // 0..63
    const int c0 = (tid & 3) * 8;    // 0,8,16,24

    const float* Af = (const float*)Av;
    const u16*   Ab = (const u16*)Av;
    const float* Bp = Bt + (size_t)(n0 + r0) * K + c0;

    for (int k0 = 0; k0 < K; k0 += 32) {
        __syncthreads();
        short8 a0, a1;
        if (MODE == 3) {
            a0 = *(const short8*)(Ab + (size_t)(m0 + r0) * K + c0 + k0);
            a1 = *(const short8*)(Ab + (size_t)(m0 + r0 + 64) * K + c0 + k0);
        } else {
            a0 = cvt8(Af + (size_t)(m0 + r0) * K + c0 + k0);
            a1 = cvt8(Af + (size_t)(m0 + r0 + 64) * K + c0 + k0);
        }
        short8 b0 = cvt8(Bp + k0);
        short8 b1 = cvt8(Bp + k0 + (size_t)64 * K);
        *(short8*)(As + r0 * 40 + c0)        = a0;
        *(short8*)(As + (r0 + 64) * 40 + c0) = a1;
        *(short8*)(Bs + r0 * 40 + c0)        = b0;
        *(short8*)(Bs + (r0 + 64) * 40 + c0) = b1;
        __syncthreads();
        short8 af[4], bfr[4];
#pragma unroll
        for (int i = 0; i < 4; ++i)
            af[i] = *(const short8*)(As + (wm + i * 16 + l15) * 40 + quad * 8);
#pragma unroll
        for (int j = 0; j < 4; ++j)
            bfr[j] = *(const short8*)(Bs + (wn + j * 16 + l15) * 40 + quad * 8);
#pragma unroll
        for (int i = 0; i < 4; ++i)
#pragma unroll
            for (int j = 0; j < 4; ++j)
                acc[i][j] = __builtin_amdgcn_mfma_f32_16x16x32_bf16(af[i], bfr[j], acc[i][j], 0, 0, 0);
    }

    if (MODE != 2) {
#pragma unroll
        for (int j = 0; j < 4; ++j) {
            const int n = n0 + wn + j * 16 + l15;
            const float bv = bias[n];
#pragma unroll
            for (int i = 0; i < 4; ++i) {
#pragma unroll
                for (int r = 0; r < 4; ++r) {
                    const int m = m0 + wm + i * 16 + quad * 4 + r;
                    const float vv = acc[i][j][r] + bv;
                    if (MODE == 3) {
                        ((float*)Cv)[(size_t)m * ND + n] = vv;
                    } else {
                        const size_t idx = ((size_t)((m >> 11) * NH + (n >> 6)) << 17)
                                         + (size_t)(m & (NS - 1)) * NDK + (n & (NDK - 1));
                        ((u16*)Cv)[idx] = f2bf(vv);
                    }
                }
            }
        }
    } else {
#pragma unroll
        for (int i = 0; i < 4; ++i) {
#pragma unroll
            for (int r = 0; r < 4; ++r) {
                const int m = m0 + wm + i * 16 + quad * 4 + r;   // feature index
                const float bv = bias[m];
#pragma unroll
                for (int j = 0; j < 4; ++j) {
                    const int n = n0 + wn + j * 16 + l15;        // b*S+s index
                    const float vv = acc[i][j][r] + bv;
                    const size_t idx = ((size_t)((n >> 11) * NH + (m >> 6)) << 17)
                                     + (size_t)(m & (NDK - 1)) * NS + (n & (NS - 1));
                    ((u16*)Cv)[idx] = f2bf(vv);
                }
            }
        }
    }
}

// ---------------------------------------------------------------------------
// Causal attention, barrier-free rewrite.
// One block = 64 q-rows of one (b,h); 4 independent waves x 16 rows each.
// Q hoisted to registers. K/V MFMA fragments loaded DIRECTLY from global
// (L1/L2-resident: 256KB per bh) -- no LDS staging, no __syncthreads().
// LDS only holds the per-wave P transpose buffer (C-layout -> A-layout)
// for the PV MFMA. attn fp32 written straight from registers.
// ---------------------------------------------------------------------------
__global__ __launch_bounds__(256) void attn64(
    const u16* __restrict__ Qh, const u16* __restrict__ Kh,
    const u16* __restrict__ Vt, float* __restrict__ attn,
    u16* __restrict__ X)
{
    __shared__ __align__(16) u16 Ps[4][16 * 72];   // per-wave 16x64 band, 9 KB total
    const int tid  = threadIdx.x;
    const int lane = tid & 63;
    const int w    = tid >> 6;
    const int l15  = lane & 15;
    const int quad = lane >> 4;
    // heavy-first: high q-tiles (most k-tiles) dispatch first
    const int q0 = ((int)gridDim.x - 1 - (int)blockIdx.x) * 64;
    const int bh = blockIdx.y;
    const u16* Qp = Qh + ((size_t)bh * NS + q0) * NDK;
    const u16* Kp = Kh + (size_t)bh * NS * NDK;
    const u16* Vp = Vt + (size_t)bh * NDK * NS;
    u16* Pw = &Ps[w][0];

    // Q fragments for this wave's 16 rows, hoisted once
    short8 aq[2];
#pragma unroll
    for (int ks = 0; ks < 2; ++ks)
        aq[ks] = *(const short8*)(Qp + (size_t)(w * 16 + l15) * NDK + ks * 32 + quad * 8);

    const int qrow = q0 + w * 16 + quad * 4;   // + r gives global q row

    float m_r[4], l_r[4];
#pragma unroll
    for (int r = 0; r < 4; ++r) { m_r[r] = -1e30f; l_r[r] = 0.f; }

    const int nkt = (q0 >> 6) + 1;

    // ---------------- phase 1: row stats (online max/sum) ----------------
    for (int kt = 0; kt < nkt; ++kt) {
        const int k0 = kt * 64;
        short8 bk[2][4];
#pragma unroll
        for (int ks = 0; ks < 2; ++ks)
#pragma unroll
            for (int j = 0; j < 4; ++j)
                bk[ks][j] = *(const short8*)(Kp + (size_t)(k0 + j * 16 + l15) * NDK + ks * 32 + quad * 8);

        f32x4 sa[4];
        const f32x4 zf = {0.f, 0.f, 0.f, 0.f};
#pragma unroll
        for (int j = 0; j < 4; ++j) sa[j] = zf;
#pragma unroll
        for (int ks = 0; ks < 2; ++ks)
#pragma unroll
            for (int j = 0; j < 4; ++j)
                sa[j] = __builtin_amdgcn_mfma_f32_16x16x32_bf16(aq[ks], bk[ks][j], sa[j], 0, 0, 0);

        float s[4][4];
        if (kt == nkt - 1) {       // diagonal tile: apply causal mask
#pragma unroll
            for (int j = 0; j < 4; ++j) {
                const int kg = k0 + j * 16 + l15;
#pragma unroll
                for (int r = 0; r < 4; ++r)
                    s[j][r] = (kg > qrow + r) ? -1e9f : sa[j][r] * 0.125f;
            }
        } else {                   // fully unmasked
#pragma unroll
            for (int j = 0; j < 4; ++j)
#pragma unroll
                for (int r = 0; r < 4; ++r)
                    s[j][r] = sa[j][r] * 0.125f;
        }
#pragma unroll
        for (int r = 0; r < 4; ++r) {
            float mx = fmaxf(fmaxf(s[0][r], s[1][r]), fmaxf(s[2][r], s[3][r]));
            mx = fmaxf(mx, __shfl_xor(mx, 1));
            mx = fmaxf(mx, __shfl_xor(mx, 2));
            mx = fmaxf(mx, __shfl_xor(mx, 4));
            mx = fmaxf(mx, __shfl_xor(mx, 8));
            const float mn = fmaxf(m_r[r], mx);
            float sum = __expf(s[0][r] - mn) + __expf(s[1][r] - mn)
                      + __expf(s[2][r] - mn) + __expf(s[3][r] - mn);
            sum += __shfl_xor(sum, 1);
            sum += __shfl_xor(sum, 2);
            sum += __shfl_xor(sum, 4);
            sum += __shfl_xor(sum, 8);
            l_r[r] = l_r[r] * __expf(m_r[r] - mn) + sum;
            m_r[r] = mn;
        }
    }

    float rl[4];
#pragma unroll
    for (int r = 0; r < 4; ++r) rl[r] = 1.f / l_r[r];

    f32x4 oa[4];
    {
        const f32x4 zf = {0.f, 0.f, 0.f, 0.f};
#pragma unroll
        for (int j = 0; j < 4; ++j) oa[j] = zf;
    }

    float* arow = attn + (size_t)bh * NS * NS;

    // ---------------- phase 2: attn write + O accumulate ----------------
    for (int kt = 0; kt < nkt; ++kt) {
        const int k0 = kt * 64;
        const bool diag = (kt == nkt - 1);

        short8 bk[2][4];
#pragma unroll
        for (int ks = 0; ks < 2; ++ks)
#pragma unroll
            for (int j = 0; j < 4; ++j)
                bk[ks][j] = *(const short8*)(Kp + (size_t)(k0 + j * 16 + l15) * NDK + ks * 32 + quad * 8);

        f32x4 sa[4];
        const f32x4 zf = {0.f, 0.f, 0.f, 0.f};
#pragma unroll
        for (int j = 0; j < 4; ++j) sa[j] = zf;
#pragma unroll
        for (int ks = 0; ks < 2; ++ks)
#pragma unroll
            for (int j = 0; j < 4; ++j)
                sa[j] = __builtin_amdgcn_mfma_f32_16x16x32_bf16(aq[ks], bk[ks][j], sa[j], 0, 0, 0);

        // p = exp(s - m)/l -> fp32 attn store direct from regs + bf16 to Ps
#pragma unroll
        for (int r = 0; r < 4; ++r) {
            float* ar = arow + (size_t)(qrow + r) * NS + k0 + l15;
#pragma unroll
            for (int j = 0; j < 4; ++j) {
                float p = __expf(sa[j][r] * 0.125f - m_r[r]) * rl[r];
                if (diag && (k0 + j * 16 + l15 > qrow + r)) p = 0.f;
                ar[j * 16] = p;                                   // 64B/16-lane coalesced
                Pw[(quad * 4 + r) * 72 + j * 16 + l15] = f2bf(p); // C-layout -> LDS
            }
        }

        // V fragments direct from global, P A-fragments from own LDS band
        short8 bv[2][4];
#pragma unroll
        for (int ks = 0; ks < 2; ++ks)
#pragma unroll
            for (int j = 0; j < 4; ++j)
                bv[ks][j] = *(const short8*)(Vp + (size_t)(j * 16 + l15) * NS + k0 + ks * 32 + quad * 8);

        short8 pa[2];
#pragma unroll
        for (int ks = 0; ks < 2; ++ks)
            pa[ks] = *(const short8*)(Pw + l15 * 72 + ks * 32 + quad * 8);

#pragma unroll
        for (int ks = 0; ks < 2; ++ks)
#pragma unroll
            for (int j = 0; j < 4; ++j)
                oa[j] = __builtin_amdgcn_mfma_f32_16x16x32_bf16(pa[ks], bv[ks][j], oa[j], 0, 0, 0);
    }

    // fully-masked tiles: fp32 zeros
    {
        const int row = lane >> 2;          // 0..15
        const int cc  = (lane & 3) * 16;    // 0,16,32,48
        const int qg  = q0 + w * 16 + row;
        const float4 z = make_float4(0.f, 0.f, 0.f, 0.f);
        for (int kt = nkt; kt < NS / 64; ++kt) {
            float* dst = arow + (size_t)qg * NS + kt * 64 + cc;
#pragma unroll
            for (int t = 0; t < 4; ++t) *(float4*)(dst + t * 4) = z;
        }
    }

    // store O to X[b, q, h*DK+dk]  (bf16 workspace)
    const int b = bh >> 4, h = bh & 15;
#pragma unroll
    for (int j = 0; j < 4; ++j) {
        const int dk = j * 16 + l15;
#pragma unroll
        for (int r = 0; r < 4; ++r) {
            const int qg = qrow + r;
            X[((size_t)b * NS + qg) * ND + (size_t)h * NDK + dk] = f2bf(oa[j][r]);
        }
    }
}

// ---------------------------------------------------------------------------
extern "C" void kernel_launch(void* const* d_in, const int* in_sizes, int n_in,
                              void* d_out, int out_size, void* d_ws, size_t ws_size,
                              hipStream_t stream) {
    const float* q    = (const float*)d_in[0];
    const float* k    = (const float*)d_in[1];
    const float* v    = (const float*)d_in[2];
    // d_in[3] = mask (int32 tril) — causality computed arithmetically
    const float* wq_w = (const float*)d_in[4];
    const float* wq_b = (const float*)d_in[5];
    const float* wk_w = (const float*)d_in[6];
    const float* wk_b = (const float*)d_in[7];
    const float* wv_w = (const float*)d_in[8];
    const float* wv_b = (const float*)d_in[9];
    const float* wo_w = (const float*)d_in[10];
    const float* wo_b = (const float*)d_in[11];

    float* out  = (float*)d_out;
    float* attn = out + (size_t)NB * NS * ND;   // second tuple element

    u16* ws = (u16*)d_ws;
    const size_t seg = (size_t)NB * NH * NS * NDK;   // 8388608 elems (bf16)
    u16* Qh = ws;
    u16* Kh = Qh + seg;
    u16* Vt = Kh + seg;
    u16* X  = Vt + seg;

    gemm128<0><<<dim3(512), dim3(256), 0, stream>>>((const void*)q, wq_w, wq_b, (void*)Qh);
    gemm128<0><<<dim3(512), dim3(256), 0, stream>>>((const void*)k, wk_w, wk_b, (void*)Kh);
    gemm128<2><<<dim3(512), dim3(256), 0, stream>>>((const void*)wv_w, v, wv_b, (void*)Vt);
    attn64<<<dim3(NS / 64, NB * NH), dim3(256), 0, stream>>>(Qh, Kh, Vt, attn, X);
    gemm128<3><<<dim3(512), dim3(256), 0, stream>>>((const void*)X, wo_w, wo_b, (void*)out);
}

// Round 2
// 1545.330 us; speedup vs baseline: 1.4373x; 1.4373x over previous
//
#include <hip/hip_runtime.h>
#include <stdint.h>

typedef unsigned short u16;
typedef short short8 __attribute__((ext_vector_type(8)));
typedef float f32x4 __attribute__((ext_vector_type(4)));
typedef float f4v __attribute__((ext_vector_type(4)));

#define NB 4
#define NS 2048
#define ND 1024
#define NH 16
#define NDK 64

__device__ __forceinline__ u16 f2bf(float f) {
    union { float f; uint32_t i; } x; x.f = f;
    uint32_t r = x.i + 0x7FFFu + ((x.i >> 16) & 1u);
    return (u16)(r >> 16);
}
__device__ __forceinline__ float bf2f(u16 u) {
    union { uint32_t i; float f; } x; x.i = ((uint32_t)u) << 16; return x.f;
}
__device__ __forceinline__ short8 cvt8(const float* __restrict__ p) {
    float4 a = *(const float4*)p;
    float4 b = *(const float4*)(p + 4);
    short8 r;
    r[0] = (short)f2bf(a.x); r[1] = (short)f2bf(a.y);
    r[2] = (short)f2bf(a.z); r[3] = (short)f2bf(a.w);
    r[4] = (short)f2bf(b.x); r[5] = (short)f2bf(b.y);
    r[6] = (short)f2bf(b.z); r[7] = (short)f2bf(b.w);
    return r;
}

// ---------------------------------------------------------------------------
// 128x128x32 MFMA GEMM: C = A[M,K] * Bt[N,K]^T + bias   (UNCHANGED this round)
// ---------------------------------------------------------------------------
template<int MODE>
__global__ __launch_bounds__(256) void gemm128(
    const void* __restrict__ Av, const float* __restrict__ Bt,
    const float* __restrict__ bias, void* __restrict__ Cv)
{
    __shared__ __align__(16) u16 As[128 * 40];
    __shared__ __align__(16) u16 Bs[128 * 40];
    const int tid  = threadIdx.x;
    const int lane = tid & 63;
    const int w    = tid >> 6;
    const int wm   = (w >> 1) * 64;
    const int wn   = (w & 1) * 64;
    const int l15  = lane & 15;
    const int quad = lane >> 4;
    const int K    = 1024;
    int mt, nt;
    if (MODE == 2) { mt = blockIdx.x & 7; nt = blockIdx.x >> 3; }
    else           { mt = blockIdx.x >> 3; nt = blockIdx.x & 7; }
    const int m0 = mt * 128, n0 = nt * 128;

    f32x4 acc[4][4];
    const f32x4 zf = {0.f, 0.f, 0.f, 0.f};
#pragma unroll
    for (int i = 0; i < 4; ++i)
#pragma unroll
        for (int j = 0; j < 4; ++j) acc[i][j] = zf;

    const int r0 = tid >> 2;         // 0..63
    const int c0 = (tid & 3) * 8;    // 0,8,16,24

    const float* Af = (const float*)Av;
    const u16*   Ab = (const u16*)Av;
    const float* Bp = Bt + (size_t)(n0 + r0) * K + c0;

    for (int k0 = 0; k0 < K; k0 += 32) {
        __syncthreads();
        short8 a0, a1;
        if (MODE == 3) {
            a0 = *(const short8*)(Ab + (size_t)(m0 + r0) * K + c0 + k0);
            a1 = *(const short8*)(Ab + (size_t)(m0 + r0 + 64) * K + c0 + k0);
        } else {
            a0 = cvt8(Af + (size_t)(m0 + r0) * K + c0 + k0);
            a1 = cvt8(Af + (size_t)(m0 + r0 + 64) * K + c0 + k0);
        }
        short8 b0 = cvt8(Bp + k0);
        short8 b1 = cvt8(Bp + k0 + (size_t)64 * K);
        *(short8*)(As + r0 * 40 + c0)        = a0;
        *(short8*)(As + (r0 + 64) * 40 + c0) = a1;
        *(short8*)(Bs + r0 * 40 + c0)        = b0;
        *(short8*)(Bs + (r0 + 64) * 40 + c0) = b1;
        __syncthreads();
        short8 af[4], bfr[4];
#pragma unroll
        for (int i = 0; i < 4; ++i)
            af[i] = *(const short8*)(As + (wm + i * 16 + l15) * 40 + quad * 8);
#pragma unroll
        for (int j = 0; j < 4; ++j)
            bfr[j] = *(const short8*)(Bs + (wn + j * 16 + l15) * 40 + quad * 8);
#pragma unroll
        for (int i = 0; i < 4; ++i)
#pragma unroll
            for (int j = 0; j < 4; ++j)
                acc[i][j] = __builtin_amdgcn_mfma_f32_16x16x32_bf16(af[i], bfr[j], acc[i][j], 0, 0, 0);
    }

    if (MODE != 2) {
#pragma unroll
        for (int j = 0; j < 4; ++j) {
            const int n = n0 + wn + j * 16 + l15;
            const float bv = bias[n];
#pragma unroll
            for (int i = 0; i < 4; ++i) {
#pragma unroll
                for (int r = 0; r < 4; ++r) {
                    const int m = m0 + wm + i * 16 + quad * 4 + r;
                    const float vv = acc[i][j][r] + bv;
                    if (MODE == 3) {
                        ((float*)Cv)[(size_t)m * ND + n] = vv;
                    } else {
                        const size_t idx = ((size_t)((m >> 11) * NH + (n >> 6)) << 17)
                                         + (size_t)(m & (NS - 1)) * NDK + (n & (NDK - 1));
                        ((u16*)Cv)[idx] = f2bf(vv);
                    }
                }
            }
        }
    } else {
#pragma unroll
        for (int i = 0; i < 4; ++i) {
#pragma unroll
            for (int r = 0; r < 4; ++r) {
                const int m = m0 + wm + i * 16 + quad * 4 + r;   // feature index
                const float bv = bias[m];
#pragma unroll
                for (int j = 0; j < 4; ++j) {
                    const int n = n0 + wn + j * 16 + l15;        // b*S+s index
                    const float vv = acc[i][j][r] + bv;
                    const size_t idx = ((size_t)((n >> 11) * NH + (m >> 6)) << 17)
                                     + (size_t)(m & (NDK - 1)) * NS + (n & (NS - 1));
                    ((u16*)Cv)[idx] = f2bf(vv);
                }
            }
        }
    }
}

// ---------------------------------------------------------------------------
// Causal attention, cooperative-staged, 128 q-rows per block.
// 4 waves; wave w owns rows [w*32, w*32+32) of the q-block, as two 16-row
// MFMA groups (g=0,1). K/V tiles staged block-cooperatively into LDS with
// reg-prefetch (issue loads for tile t+1 right after the barrier, so HBM
// latency hides under tile t's compute). Q hoisted in registers. attn fp32
// written nontemporal, directly from MFMA C-layout regs. Per-group tile
// bounds gkt[g] skip fully-masked work; zero region streamed up front.
// ---------------------------------------------------------------------------
__global__ __launch_bounds__(256) void attn128(
    const u16* __restrict__ Qh, const u16* __restrict__ Kh,
    const u16* __restrict__ Vt, float* __restrict__ attn,
    u16* __restrict__ X)
{
    __shared__ __align__(16) u16 Ks[64 * 72];        // 9.2 KB
    __shared__ __align__(16) u16 Vs[64 * 72];        // 9.2 KB
    __shared__ __align__(16) u16 Ps[4][32 * 72];     // 18.4 KB (per-wave P bands)
    const int tid  = threadIdx.x;
    const int lane = tid & 63;
    const int w    = tid >> 6;
    const int l15  = lane & 15;
    const int quad = lane >> 4;
    // heavy-first: high q-tiles dispatch first
    const int q0 = (15 - (int)blockIdx.x) * 128;
    const int bh = blockIdx.y;
    const u16* Qp = Qh + ((size_t)bh * NS + q0) * NDK;
    const u16* Kp = Kh + (size_t)bh * NS * NDK;
    const u16* Vp = Vt + (size_t)bh * NDK * NS;
    u16* Pw = &Ps[w][0];
    float* arow = attn + (size_t)bh * NS * NS;

    // cooperative staging map: thread -> (row, 32B chunk)
    const int sr = tid >> 2;          // 0..63
    const int sc = (tid & 3) * 16;    // u16 units: 0,16,32,48

    const int gbase[2] = { q0 + w * 32, q0 + w * 32 + 16 };
    const int gkt[2]   = { ((gbase[0] + 15) >> 6) + 1, ((gbase[1] + 15) >> 6) + 1 };
    const int nkt = (q0 >> 6) + 2;    // tiles the block must stage

    // ---- streaming zero-fill of fully-masked attn region (nontemporal) ----
    {
        const f4v z = {0.f, 0.f, 0.f, 0.f};
#pragma unroll
        for (int g = 0; g < 2; ++g) {
            const int qg = gbase[g] + (lane >> 2);
            float* dst = arow + (size_t)qg * NS;
            for (int c = gkt[g] * 64 + (lane & 3) * 4; c < NS; c += 16)
                __builtin_nontemporal_store(z, (f4v*)(dst + c));
        }
    }

    // ---- Q fragments hoisted ----
    short8 aq[2][2];
#pragma unroll
    for (int g = 0; g < 2; ++g)
#pragma unroll
        for (int ks = 0; ks < 2; ++ks)
            aq[g][ks] = *(const short8*)(Qp + (size_t)(w * 32 + g * 16 + l15) * NDK + ks * 32 + quad * 8);

    float m_r[2][4], l_r[2][4];
#pragma unroll
    for (int g = 0; g < 2; ++g)
#pragma unroll
        for (int r = 0; r < 4; ++r) { m_r[g][r] = -1e30f; l_r[g][r] = 0.f; }

    // ---------------- phase 1: row stats ----------------
    uint4 kf0 = *(const uint4*)(Kp + (size_t)sr * NDK + sc);
    uint4 kf1 = *(const uint4*)(Kp + (size_t)sr * NDK + sc + 8);
    for (int kt = 0; kt < nkt; ++kt) {
        const int k0 = kt * 64;
        __syncthreads();
        *(uint4*)(Ks + sr * 72 + sc)     = kf0;
        *(uint4*)(Ks + sr * 72 + sc + 8) = kf1;
        __syncthreads();
        if (kt + 1 < nkt) {
            kf0 = *(const uint4*)(Kp + (size_t)(k0 + 64 + sr) * NDK + sc);
            kf1 = *(const uint4*)(Kp + (size_t)(k0 + 64 + sr) * NDK + sc + 8);
        }
        if (kt >= gkt[1]) continue;          // both groups fully masked

        short8 bk[2][4];
#pragma unroll
        for (int ks = 0; ks < 2; ++ks)
#pragma unroll
            for (int j = 0; j < 4; ++j)
                bk[ks][j] = *(const short8*)(Ks + (j * 16 + l15) * 72 + ks * 32 + quad * 8);

#pragma unroll
        for (int g = 0; g < 2; ++g) {
            if (kt >= gkt[g]) continue;
            f32x4 sg[4];
            const f32x4 zf = {0.f, 0.f, 0.f, 0.f};
#pragma unroll
            for (int j = 0; j < 4; ++j) sg[j] = zf;
#pragma unroll
            for (int ks = 0; ks < 2; ++ks)
#pragma unroll
                for (int j = 0; j < 4; ++j)
                    sg[j] = __builtin_amdgcn_mfma_f32_16x16x32_bf16(aq[g][ks], bk[ks][j], sg[j], 0, 0, 0);

            const int qg = gbase[g] + quad * 4;
            float s[4][4];
            if (k0 + 63 > gbase[g]) {        // tile may touch the diagonal
#pragma unroll
                for (int j = 0; j < 4; ++j) {
                    const int kg = k0 + j * 16 + l15;
#pragma unroll
                    for (int r = 0; r < 4; ++r)
                        s[j][r] = (kg > qg + r) ? -1e9f : sg[j][r] * 0.125f;
                }
            } else {
#pragma unroll
                for (int j = 0; j < 4; ++j)
#pragma unroll
                    for (int r = 0; r < 4; ++r)
                        s[j][r] = sg[j][r] * 0.125f;
            }
#pragma unroll
            for (int r = 0; r < 4; ++r) {
                float mx = fmaxf(fmaxf(s[0][r], s[1][r]), fmaxf(s[2][r], s[3][r]));
                mx = fmaxf(mx, __shfl_xor(mx, 1));
                mx = fmaxf(mx, __shfl_xor(mx, 2));
                mx = fmaxf(mx, __shfl_xor(mx, 4));
                mx = fmaxf(mx, __shfl_xor(mx, 8));
                const float mn = fmaxf(m_r[g][r], mx);
                float sum = __expf(s[0][r] - mn) + __expf(s[1][r] - mn)
                          + __expf(s[2][r] - mn) + __expf(s[3][r] - mn);
                sum += __shfl_xor(sum, 1);
                sum += __shfl_xor(sum, 2);
                sum += __shfl_xor(sum, 4);
                sum += __shfl_xor(sum, 8);
                l_r[g][r] = l_r[g][r] * __expf(m_r[g][r] - mn) + sum;
                m_r[g][r] = mn;
            }
        }
    }

    float rl[2][4];
#pragma unroll
    for (int g = 0; g < 2; ++g)
#pragma unroll
        for (int r = 0; r < 4; ++r) rl[g][r] = 1.f / l_r[g][r];

    f32x4 oa[2][4];
    {
        const f32x4 zf = {0.f, 0.f, 0.f, 0.f};
#pragma unroll
        for (int g = 0; g < 2; ++g)
#pragma unroll
            for (int j = 0; j < 4; ++j) oa[g][j] = zf;
    }

    // ---------------- phase 2: attn write + O accumulate ----------------
    uint4 vf0, vf1;
    kf0 = *(const uint4*)(Kp + (size_t)sr * NDK + sc);
    kf1 = *(const uint4*)(Kp + (size_t)sr * NDK + sc + 8);
    vf0 = *(const uint4*)(Vp + (size_t)sr * NS + sc);
    vf1 = *(const uint4*)(Vp + (size_t)sr * NS + sc + 8);
    for (int kt = 0; kt < nkt; ++kt) {
        const int k0 = kt * 64;
        __syncthreads();
        *(uint4*)(Ks + sr * 72 + sc)     = kf0;
        *(uint4*)(Ks + sr * 72 + sc + 8) = kf1;
        *(uint4*)(Vs + sr * 72 + sc)     = vf0;
        *(uint4*)(Vs + sr * 72 + sc + 8) = vf1;
        __syncthreads();
        if (kt + 1 < nkt) {
            kf0 = *(const uint4*)(Kp + (size_t)(k0 + 64 + sr) * NDK + sc);
            kf1 = *(const uint4*)(Kp + (size_t)(k0 + 64 + sr) * NDK + sc + 8);
            vf0 = *(const uint4*)(Vp + (size_t)sr * NS + k0 + 64 + sc);
            vf1 = *(const uint4*)(Vp + (size_t)sr * NS + k0 + 64 + sc + 8);
        }
        if (kt >= gkt[1]) continue;

        short8 bk[2][4];
#pragma unroll
        for (int ks = 0; ks < 2; ++ks)
#pragma unroll
            for (int j = 0; j < 4; ++j)
                bk[ks][j] = *(const short8*)(Ks + (j * 16 + l15) * 72 + ks * 32 + quad * 8);

#pragma unroll
        for (int g = 0; g < 2; ++g) {
            if (kt >= gkt[g]) continue;
            f32x4 sg[4];
            const f32x4 zf = {0.f, 0.f, 0.f, 0.f};
#pragma unroll
            for (int j = 0; j < 4; ++j) sg[j] = zf;
#pragma unroll
            for (int ks = 0; ks < 2; ++ks)
#pragma unroll
                for (int j = 0; j < 4; ++j)
                    sg[j] = __builtin_amdgcn_mfma_f32_16x16x32_bf16(aq[g][ks], bk[ks][j], sg[j], 0, 0, 0);

            const int qg = gbase[g] + quad * 4;
            const bool dm = (k0 + 63 > gbase[g]);
#pragma unroll
            for (int r = 0; r < 4; ++r) {
                float* ar = arow + (size_t)(qg + r) * NS + k0 + l15;
#pragma unroll
                for (int j = 0; j < 4; ++j) {
                    float sv = sg[j][r] * 0.125f;
                    if (dm && (k0 + j * 16 + l15 > qg + r)) sv = -1e9f;
                    const float p = __expf(sv - m_r[g][r]) * rl[g][r];
                    __builtin_nontemporal_store(p, ar + j * 16);
                    Pw[(g * 16 + quad * 4 + r) * 72 + j * 16 + l15] = f2bf(p);
                }
            }
        }

        short8 bv[2][4];
#pragma unroll
        for (int ks = 0; ks < 2; ++ks)
#pragma unroll
            for (int j = 0; j < 4; ++j)
                bv[ks][j] = *(const short8*)(Vs + (j * 16 + l15) * 72 + ks * 32 + quad * 8);

#pragma unroll
        for (int g = 0; g < 2; ++g) {
            if (kt >= gkt[g]) continue;
            short8 pa[2];
#pragma unroll
            for (int ks = 0; ks < 2; ++ks)
                pa[ks] = *(const short8*)(Pw + (g * 16 + l15) * 72 + ks * 32 + quad * 8);
#pragma unroll
            for (int ks = 0; ks < 2; ++ks)
#pragma unroll
                for (int j = 0; j < 4; ++j)
                    oa[g][j] = __builtin_amdgcn_mfma_f32_16x16x32_bf16(pa[ks], bv[ks][j], oa[g][j], 0, 0, 0);
        }
    }

    // ---- store O to X[b, q, h*DK+dk] (bf16 workspace) ----
    const int b = bh >> 4, h = bh & 15;
#pragma unroll
    for (int g = 0; g < 2; ++g) {
        const int qgb = gbase[g] + quad * 4;
#pragma unroll
        for (int j = 0; j < 4; ++j) {
            const int dk = j * 16 + l15;
#pragma unroll
            for (int r = 0; r < 4; ++r) {
                X[((size_t)b * NS + (qgb + r)) * ND + (size_t)h * NDK + dk] = f2bf(oa[g][j][r]);
            }
        }
    }
}

// ---------------------------------------------------------------------------
extern "C" void kernel_launch(void* const* d_in, const int* in_sizes, int n_in,
                              void* d_out, int out_size, void* d_ws, size_t ws_size,
                              hipStream_t stream) {
    const float* q    = (const float*)d_in[0];
    const float* k    = (const float*)d_in[1];
    const float* v    = (const float*)d_in[2];
    // d_in[3] = mask (int32 tril) — causality computed arithmetically
    const float* wq_w = (const float*)d_in[4];
    const float* wq_b = (const float*)d_in[5];
    const float* wk_w = (const float*)d_in[6];
    const float* wk_b = (const float*)d_in[7];
    const float* wv_w = (const float*)d_in[8];
    const float* wv_b = (const float*)d_in[9];
    const float* wo_w = (const float*)d_in[10];
    const float* wo_b = (const float*)d_in[11];

    float* out  = (float*)d_out;
    float* attn = out + (size_t)NB * NS * ND;   // second tuple element

    u16* ws = (u16*)d_ws;
    const size_t seg = (size_t)NB * NH * NS * NDK;   // 8388608 elems (bf16)
    u16* Qh = ws;
    u16* Kh = Qh + seg;
    u16* Vt = Kh + seg;
    u16* X  = Vt + seg;

    gemm128<0><<<dim3(512), dim3(256), 0, stream>>>((const void*)q, wq_w, wq_b, (void*)Qh);
    gemm128<0><<<dim3(512), dim3(256), 0, stream>>>((const void*)k, wk_w, wk_b, (void*)Kh);
    gemm128<2><<<dim3(512), dim3(256), 0, stream>>>((const void*)wv_w, v, wv_b, (void*)Vt);
    attn128<<<dim3(NS / 128, NB * NH), dim3(256), 0, stream>>>(Qh, Kh, Vt, attn, X);
    gemm128<3><<<dim3(512), dim3(256), 0, stream>>>((const void*)X, wo_w, wo_b, (void*)out);
}